// Round 7
// baseline (7057.095 us; speedup 1.0000x reference)
//
#include <hip/hip_runtime.h>
#include <math.h>

// Problem constants
#define BN   128      // batch
#define TN   1440     // timesteps
#define HN   512      // hidden
#define GBn  8        // batch groups
#define BSn  16       // batches per group
#define GCn  32       // column groups
#define HCn  16       // h-cols per WG

using f16 = _Float16;
typedef f16   f16x8 __attribute__((ext_vector_type(8)));
typedef float f32x4 __attribute__((ext_vector_type(4)));
typedef unsigned int       uint32;
typedef unsigned long long u64;
typedef uint32 u32x4 __attribute__((ext_vector_type(4)));

// ws layout (bytes):
//   [0,1024)             flags[8][32] int
//   [1024,2048)          scal: [0]=half_tau, [1]=trigger
//   [2048,526336)        hbufP uint32 [2 buf][128 b][512 k]  packed (lo16=f16 hi, hi16=f16 lo*2048)
//   [526336,1263616)     xsf f32 [128][1440]
#define OFF_SCAL 1024
#define OFF_HBUF 2048
#define OFF_XSF  (2048 + 2 * BN * HN * 4)

// ---------------- K0: scalar prep (grads -> half_tau, trigger) ----------------
__global__ void k_prep(const float* __restrict__ w_ih, float* __restrict__ scal) {
    __shared__ float ssum[4];
    float s = 0.0f;
    for (int i = threadIdx.x; i < 3 * HN * 2; i += 256) s += w_ih[i];
    for (int o = 32; o >= 1; o >>= 1) s += __shfl_down(s, o, 64);
    if ((threadIdx.x & 63) == 0) ssum[threadIdx.x >> 6] = s;
    __syncthreads();
    if (threadIdx.x == 0) {
        float tot = ssum[0] + ssum[1] + ssum[2] + ssum[3];
        float grads = tot / 3072.0f - 1.0f;
        float tau_new = 6.0f + grads * 0.1f;
        bool trig = (tau_new >= 1.0f) && (tau_new != 6.0f);
        scal[0] = rintf(tau_new * 0.5f);   // round-half-even matches jnp.round
        scal[1] = trig ? 1.0f : 0.0f;
    }
}

// ---------------- K1: NaN-fix + belief_fill (one wave per batch row) ----------------
__global__ void k_fill(const float* __restrict__ inp, const float* __restrict__ scal,
                       float* __restrict__ xsf) {
    const int b = blockIdx.x;
    const int lane = threadIdx.x;            // 0..63
    const float ht = scal[0];
    const bool trig = scal[1] != 0.0f;
    const float* xrow = inp + (size_t)b * 3 * TN;       // channel 0 = xs
    const float* mrow = xrow + 2 * TN;                   // channel 2 = mask
    const int CH = 23;                                   // 64*23 = 1472 >= 1440
    const int start = lane * CH;

    if (!trig) {
        for (int i = 0; i < CH; ++i) {
            int t = start + i;
            if (t < TN) { float x = xrow[t]; if (x != x) x = -1.0f; xsf[(size_t)b * TN + t] = x; }
        }
        return;
    }
    int pm = -1;
#pragma unroll
    for (int i = 0; i < CH; ++i) { int t = start + i; if (t < TN && mrow[t] == 1.0f) pm = t; }
    int incl = pm;
    for (int o = 1; o < 64; o <<= 1) { int v = __shfl_up(incl, o, 64); if (lane >= o) incl = max(incl, v); }
    int pexcl = __shfl_up(incl, 1, 64); if (lane == 0) pexcl = -1;
    int nm = TN;
#pragma unroll
    for (int i = CH - 1; i >= 0; --i) { int t = start + i; if (t < TN && mrow[t] == 1.0f) nm = t; }
    int incl2 = nm;
    for (int o = 1; o < 64; o <<= 1) { int v = __shfl_down(incl2, o, 64); if (lane + o < 64) incl2 = min(incl2, v); }
    int nexcl = __shfl_down(incl2, 1, 64); if (lane == 63) nexcl = TN;
    int narr[23];
    int runn = nexcl;
#pragma unroll
    for (int i = CH - 1; i >= 0; --i) {
        int t = start + i;
        if (t < TN) { if (mrow[t] == 1.0f) runn = t; narr[i] = runn; } else narr[i] = TN;
    }
    int runp = pexcl;
#pragma unroll
    for (int i = 0; i < CH; ++i) {
        int t = start + i;
        if (t >= TN) break;
        float x = xrow[t]; if (x != x) x = -1.0f;
        if (mrow[t] == 1.0f) runp = t;
        int pv = runp, nv = narr[i];
        int pc = min(max(pv, 0), TN - 1), nc = min(max(nv, 0), TN - 1);
        float xp = xrow[pc]; if (xp != xp) xp = -1.0f;
        float xn = xrow[nc]; if (xn != xn) xn = -1.0f;
        bool use_n = (nv < TN) && ((float)t >= (float)nv - ht);
        bool use_p = (pv >= 0) && ((float)t <= (float)pv + ht);
        float o = use_n ? xn : (use_p ? xp : x);
        xsf[(size_t)b * TN + t] = o;
    }
}

// ---------------- K2: persistent column-split GRU, SINGLE-WAVE workgroups ----------------
// grid 256 = 8 batch-groups x 32 col-groups; block 64 = ONE wave; 1 WG/CU; zero s_barriers.
// Inter-WG protocol identical to R2 (proven): publish sc0sc1 write-through, vmcnt drain,
// flag store; consumers poll 32 flags (lanes 0..31, monotone cache), then read via sc0sc1.
// Intra-WG: staged loads land straight in MFMA A-fragments via v_perm (hbuf holds packed
// f16hi|f16lo*2^11 words, R2 format); hi-weights VGPR-resident (192 VGPR), lo-weights in
// LDS; acc->gate transpose via small LDS buffer ordered by lgkmcnt only (single wave).
__global__ __launch_bounds__(64, 1) void k_gru(
    const float* __restrict__ inp, const float* __restrict__ w_ih,
    const float* __restrict__ w_hh, const float* __restrict__ b_ih,
    const float* __restrict__ b_hh, const float* __restrict__ w_fc,
    const float* __restrict__ b_fc, const float* __restrict__ xsf,
    uint32* __restrict__ hbufP, int* __restrict__ flags, float* __restrict__ out) {
    __shared__ __align__(16) f16x8 sBlo[48 * 65];       // lo-plane B-frags, 65-unit row pad
    __shared__ __align__(16) float sGh[3][16][20];      // acc->gate transpose
    __shared__ __align__(16) float sWi0[48], sWi1[48], sBias[48];

    const int tid  = threadIdx.x;      // 0..63 (= lane)
    const int gb   = blockIdx.x & 7;
    const int gc   = blockIdx.x >> 3;
    const int frow = tid & 15;         // MFMA m (A) / n (B) index
    const int kgrp = tid >> 4;         // MFMA k-group
    const int r    = tid >> 2;         // gate/publish batch row 0..15
    const int jq   = (tid & 3) * 4;    // gate/publish col base {0,4,8,12}

    if (tid < 48) {
        int gate = tid >> 4, jj = tid & 15;
        int grow = gate * HN + gc * HCn + jj;
        sWi0[tid]  = w_ih[grow * 2 + 0];
        sWi1[tid]  = w_ih[grow * 2 + 1];
        sBias[tid] = b_ih[grow] + b_hh[grow];
    }

    // one-time: weight fragments. hi -> VGPRs, lo*2^11 -> LDS (each lane writes/reads only
    // its own slots; 65-unit row stride => 2-way (free) bank aliasing on b128 reads).
    f16x8 bh[3][16];
#pragma unroll
    for (int g = 0; g < 3; ++g) {
        const float* wrow = w_hh + (size_t)(g * HN + gc * HCn + frow) * HN;
#pragma unroll
        for (int c = 0; c < 16; ++c) {
            const int k0 = (c * 4 + kgrp) * 8;
            f16x8 lo;
#pragma unroll
            for (int u = 0; u < 8; ++u) {
                float w = wrow[k0 + u];
                f16 hi = (f16)w;
                bh[g][c][u] = hi;
                lo[u] = (f16)((w - (float)hi) * 2048.0f);
            }
            sBlo[(g * 16 + frow) * 65 + c * 4 + kgrp] = lo;
        }
    }
    asm volatile("s_waitcnt lgkmcnt(0)" ::: "memory");

    int* myflags = flags + gb * GCn;
    const uint32* srcA = hbufP + (size_t)(gb * BSn + frow) * HN + kgrp * 8;   // buf0
    const uint32* srcB = srcA + (size_t)BN * HN;                              // buf1
    uint32* dstA = hbufP + (size_t)(gb * BSn + r) * HN + gc * HCn + jq;       // buf0
    uint32* dstB = dstA + (size_t)BN * HN;                                    // buf1
    float hv[4] = {0.f, 0.f, 0.f, 0.f};
    int fcache = 0;

    for (int t = 0; t < TN; ++t) {
        float xsv = xsf[(size_t)(gb * BSn + r) * TN + t];
        float mkv = inp[((size_t)(gb * BSn + r) * 3 + 2) * TN + t];
        // 1. poll the 32 peer flags (lanes 0..31; monotone value cache; tight loop)
        if (tid < GCn) {
            while (fcache < t)
                fcache = __hip_atomic_load(&myflags[tid], __ATOMIC_RELAXED,
                                           __HIP_MEMORY_SCOPE_AGENT);
        }
        // 2. stage: 32 pipelined dwordx4 sc0sc1 loads (2 per k-chunk), one vmcnt(0)
        const uint32* src = (t & 1) ? srcB : srcA;
        u32x4 L[32];
        asm volatile(
            "global_load_dwordx4 %0, %32, off sc0 sc1\n\t"
            "global_load_dwordx4 %1, %32, off offset:16 sc0 sc1\n\t"
            "global_load_dwordx4 %2, %32, off offset:128 sc0 sc1\n\t"
            "global_load_dwordx4 %3, %32, off offset:144 sc0 sc1\n\t"
            "global_load_dwordx4 %4, %32, off offset:256 sc0 sc1\n\t"
            "global_load_dwordx4 %5, %32, off offset:272 sc0 sc1\n\t"
            "global_load_dwordx4 %6, %32, off offset:384 sc0 sc1\n\t"
            "global_load_dwordx4 %7, %32, off offset:400 sc0 sc1\n\t"
            "global_load_dwordx4 %8, %32, off offset:512 sc0 sc1\n\t"
            "global_load_dwordx4 %9, %32, off offset:528 sc0 sc1\n\t"
            "global_load_dwordx4 %10, %32, off offset:640 sc0 sc1\n\t"
            "global_load_dwordx4 %11, %32, off offset:656 sc0 sc1\n\t"
            "global_load_dwordx4 %12, %32, off offset:768 sc0 sc1\n\t"
            "global_load_dwordx4 %13, %32, off offset:784 sc0 sc1\n\t"
            "global_load_dwordx4 %14, %32, off offset:896 sc0 sc1\n\t"
            "global_load_dwordx4 %15, %32, off offset:912 sc0 sc1\n\t"
            "global_load_dwordx4 %16, %32, off offset:1024 sc0 sc1\n\t"
            "global_load_dwordx4 %17, %32, off offset:1040 sc0 sc1\n\t"
            "global_load_dwordx4 %18, %32, off offset:1152 sc0 sc1\n\t"
            "global_load_dwordx4 %19, %32, off offset:1168 sc0 sc1\n\t"
            "global_load_dwordx4 %20, %32, off offset:1280 sc0 sc1\n\t"
            "global_load_dwordx4 %21, %32, off offset:1296 sc0 sc1\n\t"
            "global_load_dwordx4 %22, %32, off offset:1408 sc0 sc1\n\t"
            "global_load_dwordx4 %23, %32, off offset:1424 sc0 sc1\n\t"
            "global_load_dwordx4 %24, %32, off offset:1536 sc0 sc1\n\t"
            "global_load_dwordx4 %25, %32, off offset:1552 sc0 sc1\n\t"
            "global_load_dwordx4 %26, %32, off offset:1664 sc0 sc1\n\t"
            "global_load_dwordx4 %27, %32, off offset:1680 sc0 sc1\n\t"
            "global_load_dwordx4 %28, %32, off offset:1792 sc0 sc1\n\t"
            "global_load_dwordx4 %29, %32, off offset:1808 sc0 sc1\n\t"
            "global_load_dwordx4 %30, %32, off offset:1920 sc0 sc1\n\t"
            "global_load_dwordx4 %31, %32, off offset:1936 sc0 sc1\n\t"
            "s_waitcnt vmcnt(0)"
            : "=&v"(L[0]), "=&v"(L[1]), "=&v"(L[2]), "=&v"(L[3]),
              "=&v"(L[4]), "=&v"(L[5]), "=&v"(L[6]), "=&v"(L[7]),
              "=&v"(L[8]), "=&v"(L[9]), "=&v"(L[10]), "=&v"(L[11]),
              "=&v"(L[12]), "=&v"(L[13]), "=&v"(L[14]), "=&v"(L[15]),
              "=&v"(L[16]), "=&v"(L[17]), "=&v"(L[18]), "=&v"(L[19]),
              "=&v"(L[20]), "=&v"(L[21]), "=&v"(L[22]), "=&v"(L[23]),
              "=&v"(L[24]), "=&v"(L[25]), "=&v"(L[26]), "=&v"(L[27]),
              "=&v"(L[28]), "=&v"(L[29]), "=&v"(L[30]), "=&v"(L[31])
            : "v"(src)
            : "memory");
        // 3. per-chunk: perm-unpack to A-frags, 9 MFMA (3 gates x {hh, hl, lh})
        f32x4 acch[3]  = {{0.f,0.f,0.f,0.f},{0.f,0.f,0.f,0.f},{0.f,0.f,0.f,0.f}};
        f32x4 accl1[3] = {{0.f,0.f,0.f,0.f},{0.f,0.f,0.f,0.f},{0.f,0.f,0.f,0.f}};
        f32x4 accl2[3] = {{0.f,0.f,0.f,0.f},{0.f,0.f,0.f,0.f},{0.f,0.f,0.f,0.f}};
#pragma unroll
        for (int c = 0; c < 16; ++c) {
            u32x4 a = L[2 * c], b = L[2 * c + 1];
            u32x4 hq = { __builtin_amdgcn_perm(a.y, a.x, 0x05040100u),
                         __builtin_amdgcn_perm(a.w, a.z, 0x05040100u),
                         __builtin_amdgcn_perm(b.y, b.x, 0x05040100u),
                         __builtin_amdgcn_perm(b.w, b.z, 0x05040100u) };
            u32x4 lq = { __builtin_amdgcn_perm(a.y, a.x, 0x07060302u),
                         __builtin_amdgcn_perm(a.w, a.z, 0x07060302u),
                         __builtin_amdgcn_perm(b.y, b.x, 0x07060302u),
                         __builtin_amdgcn_perm(b.w, b.z, 0x07060302u) };
            f16x8 ah = __builtin_bit_cast(f16x8, hq);
            f16x8 al = __builtin_bit_cast(f16x8, lq);
#pragma unroll
            for (int g = 0; g < 3; ++g) {
                f16x8 bl = sBlo[(g * 16 + frow) * 65 + c * 4 + kgrp];
                acch[g]  = __builtin_amdgcn_mfma_f32_16x16x32_f16(ah, bh[g][c], acch[g], 0, 0, 0);
                accl1[g] = __builtin_amdgcn_mfma_f32_16x16x32_f16(ah, bl,       accl1[g], 0, 0, 0);
                accl2[g] = __builtin_amdgcn_mfma_f32_16x16x32_f16(al, bh[g][c], accl2[g], 0, 0, 0);
            }
        }
        // 4. acc -> gate transpose via LDS (single wave: lgkmcnt ordering, NO barrier)
        //    C/D: row = kgrp*4 + reg (batch), col = frow (j)
#pragma unroll
        for (int g = 0; g < 3; ++g)
#pragma unroll
            for (int q = 0; q < 4; ++q)
                sGh[g][kgrp * 4 + q][frow] =
                    acch[g][q] + (accl1[g][q] + accl2[g][q]) * (1.0f / 2048.0f);
        asm volatile("s_waitcnt lgkmcnt(0)" ::: "memory");
        float4 gr = *(const float4*)&sGh[0][r][jq];
        float4 gz = *(const float4*)&sGh[1][r][jq];
        float4 gn = *(const float4*)&sGh[2][r][jq];
        float4 w0r = *(const float4*)&sWi0[jq],      w1r = *(const float4*)&sWi1[jq],      bbr = *(const float4*)&sBias[jq];
        float4 w0z = *(const float4*)&sWi0[16 + jq], w1z = *(const float4*)&sWi1[16 + jq], bbz = *(const float4*)&sBias[16 + jq];
        float4 w0n = *(const float4*)&sWi0[32 + jq], w1n = *(const float4*)&sWi1[32 + jq], bbn = *(const float4*)&sBias[32 + jq];
        // 5. exact fp32 gate math (4 outputs/lane) + packed publish
        uint32 pk[4];
        {
            const float* grp = (const float*)&gr; const float* gzp = (const float*)&gz;
            const float* gnp = (const float*)&gn;
            const float* a0r = (const float*)&w0r; const float* a1r = (const float*)&w1r; const float* abr = (const float*)&bbr;
            const float* a0z = (const float*)&w0z; const float* a1z = (const float*)&w1z; const float* abz = (const float*)&bbz;
            const float* a0n = (const float*)&w0n; const float* a1n = (const float*)&w1n; const float* abn = (const float*)&bbn;
#pragma unroll
            for (int i = 0; i < 4; ++i) {
                float gir = fmaf(xsv, a0r[i], fmaf(mkv, a1r[i], abr[i])) + grp[i];
                float giz = fmaf(xsv, a0z[i], fmaf(mkv, a1z[i], abz[i])) + gzp[i];
                float gin = fmaf(xsv, a0n[i], fmaf(mkv, a1n[i], abn[i]));
                float rg = 1.0f / (1.0f + __expf(-gir));
                float zg = 1.0f / (1.0f + __expf(-giz));
                float ng = tanhf(gin + rg * gnp[i]);
                float hn2 = (1.0f - zg) * ng + zg * hv[i];
                hv[i] = hn2;
                f16 phi = (f16)hn2;
                f16 plo = (f16)((hn2 - (float)phi) * 2048.0f);
                pk[i] = (uint32)__builtin_bit_cast(unsigned short, phi)
                      | ((uint32)__builtin_bit_cast(unsigned short, plo) << 16);
            }
        }
        {
            u32x4 val = { pk[0], pk[1], pk[2], pk[3] };
            uint32* dst = (t & 1) ? dstA : dstB;   // write buf[(t+1)&1]
            asm volatile(
                "global_store_dwordx4 %0, %1, off sc0 sc1\n\t"
                "s_waitcnt vmcnt(0)"
                :: "v"(dst), "v"(val)
                : "memory");
        }
        if (tid == 0)
            __hip_atomic_store(&myflags[gc], t + 1, __ATOMIC_RELAXED,
                               __HIP_MEMORY_SCOPE_AGENT);
    }
    // 6. final FC: out[b] = sum_k h[b][k]*w_fc[k] + b_fc (quad-reduce over jq groups)
    const float* wf = w_fc + gc * HCn + jq;
    float part = hv[0] * wf[0] + hv[1] * wf[1] + hv[2] * wf[2] + hv[3] * wf[3];
    part += __shfl_xor(part, 1, 64);
    part += __shfl_xor(part, 2, 64);
    if ((tid & 3) == 0) {
        if (gc == 0) part += b_fc[0];
        atomicAdd(&out[gb * BSn + r], part);
    }
}

extern "C" void kernel_launch(void* const* d_in, const int* in_sizes, int n_in,
                              void* d_out, int out_size, void* d_ws, size_t ws_size,
                              hipStream_t stream) {
    const float* inp  = (const float*)d_in[0];
    const float* w_ih = (const float*)d_in[1];
    const float* w_hh = (const float*)d_in[2];
    const float* b_ih = (const float*)d_in[3];
    const float* b_hh = (const float*)d_in[4];
    const float* w_fc = (const float*)d_in[5];
    const float* b_fc = (const float*)d_in[6];
    float* out = (float*)d_out;
    char* ws = (char*)d_ws;
    int*    flags = (int*)ws;
    float*  scal  = (float*)(ws + OFF_SCAL);
    uint32* hbufP = (uint32*)(ws + OFF_HBUF);
    float*  xsf   = (float*)(ws + OFF_XSF);

    // zero: flags + scal + packed-h buf0 (= h_0 = 0); d_out (atomicAdd target)
    hipMemsetAsync(ws, 0, OFF_HBUF + BN * HN * 4, stream);
    hipMemsetAsync(d_out, 0, BN * sizeof(float), stream);
    k_prep<<<1, 256, 0, stream>>>(w_ih, scal);
    k_fill<<<BN, 64, 0, stream>>>(inp, scal, xsf);
    k_gru<<<GBn * GCn, 64, 0, stream>>>(inp, w_ih, w_hh, b_ih, b_hh, w_fc, b_fc,
                                        xsf, hbufP, flags, out);
}